// Round 6
// baseline (278.341 us; speedup 1.0000x reference)
//
#include <hip/hip_runtime.h>
#include <hip/hip_bf16.h>

// out[m, i] = sum_{j<=i} X[m, j] * W[i, j] + b[i]
// => C = X @ tril(W)^T + b  :  M=65536, N=512, K=512, fp32 in/out.
// R6: T4 counted-vmcnt double-buffered pipeline, BK=32.
//   - prep kernel bakes bf16(tril(W)) into ws (512 KB, L2-resident).
//   - A fp32 [128][32] (row = 128B = full bank sweep), B bf16 stored as
//     64 super-rows x 128B; both XOR-swizzled via pre-swizzled global source
//     (rule 21), staged by global_load_lds width=16 (6 issues/thread/tile).
//   - 2 LDS buffers, 2-deep prefetch; main loop waits vmcnt(6) (never 0),
//     raw s_barrier (no compiler drain), stage t+2 after compute.
//   - 48 KB LDS -> 3 blocks/CU.

#define TK 512
#define BM 128
#define BN 128
#define BK 32

typedef __attribute__((ext_vector_type(4))) float f32x4;
typedef __attribute__((ext_vector_type(4))) __bf16 bf16x4;
typedef __attribute__((ext_vector_type(8))) __bf16 bf16x8;

__device__ __forceinline__ void gload_lds16(const void* g, void* l) {
    __builtin_amdgcn_global_load_lds(
        (const __attribute__((address_space(1))) unsigned int*)g,
        (__attribute__((address_space(3))) unsigned int*)l, 16, 0, 0);
}

// ---- prep: Wb[i][j] = (j<=i) ? bf16(W[i][j]) : 0 ----
__global__ __launch_bounds__(256)
void prep_w_kernel(const float* __restrict__ W, __bf16* __restrict__ Wb) {
    const int tid = blockIdx.x * 256 + threadIdx.x;   // 65536 threads
    const int i  = tid >> 7;
    const int j0 = (tid & 127) * 4;
    f32x4 v = *reinterpret_cast<const f32x4*>(W + (size_t)i * TK + j0);
    bf16x4 o;
    #pragma unroll
    for (int e = 0; e < 4; ++e)
        o[e] = (j0 + e <= i) ? (__bf16)v[e] : (__bf16)0.f;
    *reinterpret_cast<bf16x4*>(Wb + (size_t)i * TK + j0) = o;
}

// ---- main GEMM ----
__global__ __launch_bounds__(256, 3)
void triu_gemm_kernel(const float* __restrict__ X, const __bf16* __restrict__ Wb,
                      const float* __restrict__ bias, float* __restrict__ out) {
    __shared__ float  As[2][BM * BK];   // 16 KB x2
    __shared__ __bf16 Bs[2][BN * BK];   // 8 KB x2  (48 KB total)

    const int bid = blockIdx.x;
    const int bm = (bid >> 2) * BM;     // n-siblings consecutive -> L3-warm X
    const int n0 = (bid & 3) * BN;
    const int nt = (n0 + BN) / BK;      // 4,8,12,16 K-tiles (triangular skip)

    const int t    = threadIdx.x;
    const int lane = t & 63;
    const int wave = t >> 6;
    const int wr   = wave >> 1, wc = wave & 1;
    const int l15  = lane & 15, l4 = lane >> 4;

    // A staging: 1024 16B-slots, 4/thread. slot p: row=p>>3, c_slot=p&7;
    // source k-chunk c_lin = c_slot ^ (row&7)  (pre-swizzled source).
    const float* sA[4]; float* dA[4];
    #pragma unroll
    for (int i = 0; i < 4; ++i) {
        const int p = i * 256 + t, row = p >> 3, cs = p & 7;
        const int cl = cs ^ (row & 7);
        sA[i] = X + (size_t)(bm + row) * TK + cl * 4;
        dA[i] = &As[0][p * 4];
    }
    // B staging: 512 16B-slots, 2/thread. slot p: sr=p>>3, c_slot=p&7;
    // c_lin = c_slot ^ (sr&7); row = sr*2 + (c_lin>>2); kc = c_lin&3.
    const __bf16* sB[2]; __bf16* dB[2];
    #pragma unroll
    for (int i = 0; i < 2; ++i) {
        const int p = i * 256 + t, sr = p >> 3, cs = p & 7;
        const int cl = cs ^ (sr & 7);
        const int row = sr * 2 + (cl >> 2), kc = cl & 3;
        sB[i] = Wb + (size_t)(n0 + row) * TK + kc * 8;
        dB[i] = &Bs[0][p * 8];
    }

    f32x4 acc[4][4];
    #pragma unroll
    for (int m = 0; m < 4; ++m)
        #pragma unroll
        for (int n = 0; n < 4; ++n)
            acc[m][n] = (f32x4){0.f, 0.f, 0.f, 0.f};

    auto stage = [&](int buf, int tt) {
        const int k0 = tt * BK;
        #pragma unroll
        for (int i = 0; i < 4; ++i)
            gload_lds16(sA[i] + k0, dA[i] + buf * (BM * BK));
        #pragma unroll
        for (int i = 0; i < 2; ++i)
            gload_lds16(sB[i] + k0, dB[i] + buf * (BN * BK));
    };

    // prologue: 2-deep prefetch (12 loads in flight)
    stage(0, 0);
    stage(1, 1);

    for (int tt = 0; tt < nt; ++tt) {
        // wait tile tt only; keep tile tt+1's 6 loads in flight across barrier
        if (tt + 1 < nt) asm volatile("s_waitcnt vmcnt(6)" ::: "memory");
        else             asm volatile("s_waitcnt vmcnt(0)" ::: "memory");
        __builtin_amdgcn_s_barrier();
        __builtin_amdgcn_sched_barrier(0);

        const int buf = tt & 1;
        bf16x8 a[4], b[4];
        #pragma unroll
        for (int m = 0; m < 4; ++m) {
            const int row = wr * 64 + m * 16 + l15;
            const int c0 = (l4 * 2)     ^ (row & 7);
            const int c1 = (l4 * 2 + 1) ^ (row & 7);
            f32x4 v0 = *reinterpret_cast<const f32x4*>(&As[buf][row * BK + c0 * 4]);
            f32x4 v1 = *reinterpret_cast<const f32x4*>(&As[buf][row * BK + c1 * 4]);
            #pragma unroll
            for (int e = 0; e < 4; ++e) a[m][e]     = (__bf16)v0[e];
            #pragma unroll
            for (int e = 0; e < 4; ++e) a[m][4 + e] = (__bf16)v1[e];
        }
        #pragma unroll
        for (int n = 0; n < 4; ++n) {
            const int row = wc * 64 + n * 16 + l15;
            const int sr  = row >> 1;
            const int c   = ((row & 1) * 4 + l4) ^ (sr & 7);
            b[n] = *reinterpret_cast<const bf16x8*>(&Bs[buf][sr * 64 + c * 8]);
        }
        #pragma unroll
        for (int m = 0; m < 4; ++m)
            #pragma unroll
            for (int n = 0; n < 4; ++n)
                acc[m][n] = __builtin_amdgcn_mfma_f32_16x16x32_bf16(
                    a[m], b[n], acc[m][n], 0, 0, 0);

        __builtin_amdgcn_s_barrier();
        __builtin_amdgcn_sched_barrier(0);
        if (tt + 2 < nt) stage(buf, tt + 2);   // refill the buffer just read
    }

    // ---- epilogue: C/D layout col = lane&15, row = (lane>>4)*4 + reg ----
    #pragma unroll
    for (int n = 0; n < 4; ++n) {
        const int col = n0 + wc * 64 + n * 16 + l15;
        const float bv = bias[col];
        #pragma unroll
        for (int m = 0; m < 4; ++m) {
            const int row0 = bm + wr * 64 + m * 16 + l4 * 4;
            #pragma unroll
            for (int j = 0; j < 4; ++j)
                out[(size_t)(row0 + j) * TK + col] = acc[m][n][j] + bv;
        }
    }
}

extern "C" void kernel_launch(void* const* d_in, const int* in_sizes, int n_in,
                              void* d_out, int out_size, void* d_ws, size_t ws_size,
                              hipStream_t stream) {
    const float* X = (const float*)d_in[0];
    const float* W = (const float*)d_in[1];
    const float* b = (const float*)d_in[2];
    float* out = (float*)d_out;
    __bf16* Wb = (__bf16*)d_ws;               // 512*512*2 = 512 KB

    prep_w_kernel<<<256, 256, 0, stream>>>(W, Wb);

    const int M = in_sizes[0] / TK;           // 65536
    triu_gemm_kernel<<<(M / BM) * (TK / BN), 256, 0, stream>>>(X, Wb, b, out);
}